// Round 1
// baseline (207.813 us; speedup 1.0000x reference)
//
#include <hip/hip_runtime.h>

typedef __attribute__((ext_vector_type(4))) float f32x4;
typedef __attribute__((ext_vector_type(8))) short short8;

#define DD 256          // feature dim
#define CC 512          // num classes (fixed by the bench's setup_inputs)
#define LDP 264         // padded LDS row stride in bf16 elems (528 B) -> 2-way max bank aliasing

__device__ __forceinline__ unsigned short f2bf(float f) {
    union { float f; unsigned u; } x; x.f = f;
    unsigned r = x.u + 0x7FFFu + ((x.u >> 16) & 1u);   // round-to-nearest-even
    return (unsigned short)(r >> 16);
}

// ---------------- K1: per-class segment sum of normalized support rows ----------------
// 512 blocks (one per class) x 256 threads (4 waves). Each wave scans a quarter of the
// label array (L2-resident, 256KB) and accumulates matching rows. Each feature row is
// read exactly once device-wide.
__global__ __launch_bounds__(256) void class_sum_kernel(
    const float4* __restrict__ S, const int* __restrict__ labels,
    float* __restrict__ sums, float* __restrict__ counts, int N_s)
{
    const int c = blockIdx.x;
    const int w = threadIdx.x >> 6, l = threadIdx.x & 63;
    const int quarter = N_s >> 2;
    const int base = w * quarter;
    const int4* lab4 = (const int4*)(labels + base);
    const int iters = quarter >> 8;   // 64 lanes * 4 labels per iter

    float ax = 0.f, ay = 0.f, az = 0.f, aw = 0.f;
    int cnt = 0;

    for (int it = 0; it < iters; ++it) {
        int4 lv = lab4[it * 64 + l];
        #pragma unroll
        for (int s = 0; s < 4; ++s) {
            int lab = (s == 0) ? lv.x : (s == 1) ? lv.y : (s == 2) ? lv.z : lv.w;
            unsigned long long m = __ballot(lab == c);
            cnt += __popcll(m);
            while (m) {
                int p = __ffsll((long long)m) - 1;
                m &= m - 1;
                int row = base + (it * 64 + p) * 4 + s;
                float4 v = S[row * 64 + l];        // lane l covers dims 4l..4l+3
                float ss = v.x*v.x + v.y*v.y + v.z*v.z + v.w*v.w;
                #pragma unroll
                for (int off = 32; off; off >>= 1) ss += __shfl_xor(ss, off);
                float inv = 1.0f / fmaxf(sqrtf(ss), 1e-8f);
                ax += v.x * inv; ay += v.y * inv; az += v.z * inv; aw += v.w * inv;
            }
        }
    }

    __shared__ float lred[4][DD];
    __shared__ float lcnt[4];
    lred[w][4*l+0] = ax; lred[w][4*l+1] = ay; lred[w][4*l+2] = az; lred[w][4*l+3] = aw;
    if (l == 0) lcnt[w] = (float)cnt;
    __syncthreads();
    int t = threadIdx.x;
    sums[c * DD + t] = lred[0][t] + lred[1][t] + lred[2][t] + lred[3][t];
    if (t == 0) counts[c] = lcnt[0] + lcnt[1] + lcnt[2] + lcnt[3];
}

// ---------------- K2a: global centroid (sum over classes of per-class sums) ----------------
// 16 blocks; block b sums 32 classes; atomicAdd partials into gsum (zero-initialized).
__global__ __launch_bounds__(256) void centroid_kernel(
    const float* __restrict__ sums, float* __restrict__ gsum)
{
    int d = threadIdx.x;
    int c0 = blockIdx.x * 32;
    float s = 0.f;
    #pragma unroll 4
    for (int c = c0; c < c0 + 32; ++c) s += sums[c * DD + d];
    atomicAdd(&gsum[d], s);
}

// ---------------- K2b: prototypes (shrink + renormalize), write bf16 P + unique_classes ----
__global__ __launch_bounds__(256) void proto_kernel(
    const float* __restrict__ sums, const float* __restrict__ counts,
    const float* __restrict__ gsum, const float* __restrict__ proto_shrink,
    unsigned short* __restrict__ Pbf, float* __restrict__ outUC, int N_s)
{
    const int c = blockIdx.x, d = threadIdx.x;
    float ps = proto_shrink[0];
    float ab = 1.0f / (1.0f + __expf(-ps));
    ab = fminf(fmaxf(ab, 0.0f), 0.4f);
    float cntv = fmaxf(counts[c], 1.0f);
    float mean = sums[c * DD + d] / cntv;
    float alpha = ab / sqrtf(cntv);
    float p = (1.0f - alpha) * mean + alpha * (gsum[d] / (float)N_s);

    float ss = p * p;
    #pragma unroll
    for (int off = 32; off; off >>= 1) ss += __shfl_xor(ss, off);
    __shared__ float l4[4];
    if ((threadIdx.x & 63) == 0) l4[threadIdx.x >> 6] = ss;
    __syncthreads();
    ss = l4[0] + l4[1] + l4[2] + l4[3];
    float inv = 1.0f / fmaxf(sqrtf(ss), 1e-8f);
    Pbf[c * DD + d] = f2bf(p * inv);
    if (d == 0) outUC[c] = (float)c;   // output 1: unique_classes (buffer read as f32)
}

// ---------------- K3: logits = normalize(q) @ P^T * scale, bf16 MFMA ----------------
// Block = 256 threads (4 waves), 64 q-rows per block. A tile (normalized q, bf16) stays
// in LDS for the whole kernel; A-frags held in registers across the full K=256.
// B (prototypes) staged 64 rows at a time into padded LDS.
__global__ __launch_bounds__(256) void logits_kernel(
    const float4* __restrict__ Q, const unsigned short* __restrict__ Pbf,
    const float* __restrict__ logit_scale, float* __restrict__ out)
{
    __shared__ unsigned short Alds[64 * LDP];   // 33.8 KB
    __shared__ unsigned short Blds[64 * LDP];   // 33.8 KB

    const int t = threadIdx.x;
    const int m0 = blockIdx.x * 64;

    // ---- phase 1: load 64 q rows, normalize, bf16 -> LDS ----
    {
        const int r = t >> 2, q4 = t & 3;       // 4 threads per row, 64 dims each
        const float4* qrow = Q + (m0 + r) * 64;
        float4 v[16];
        #pragma unroll
        for (int i = 0; i < 16; ++i) v[i] = qrow[q4 * 16 + i];
        float ss = 0.f;
        #pragma unroll
        for (int i = 0; i < 16; ++i) ss += v[i].x*v[i].x + v[i].y*v[i].y + v[i].z*v[i].z + v[i].w*v[i].w;
        ss += __shfl_xor(ss, 1); ss += __shfl_xor(ss, 2);
        float inv = 1.0f / fmaxf(sqrtf(ss), 1e-8f);
        unsigned short* dst = &Alds[r * LDP + q4 * 64];
        #pragma unroll
        for (int i = 0; i < 8; ++i) {          // pack two float4 -> 8 bf16 = 16B store
            short8 pk;
            float4 a = v[2*i], b = v[2*i+1];
            pk[0] = (short)f2bf(a.x * inv); pk[1] = (short)f2bf(a.y * inv);
            pk[2] = (short)f2bf(a.z * inv); pk[3] = (short)f2bf(a.w * inv);
            pk[4] = (short)f2bf(b.x * inv); pk[5] = (short)f2bf(b.y * inv);
            pk[6] = (short)f2bf(b.z * inv); pk[7] = (short)f2bf(b.w * inv);
            *(short8*)(dst + i * 8) = pk;
        }
    }
    __syncthreads();

    // ---- phase 2: MFMA ----
    const int w = t >> 6, l = t & 63;
    const int lrow = l & 15, lk = l >> 4;

    short8 a[8];                                // wave's 16 rows x K=256 A-fragments
    {
        const unsigned short* abase = &Alds[(16 * w + lrow) * LDP + lk * 8];
        #pragma unroll
        for (int k = 0; k < 8; ++k) a[k] = *(const short8*)(abase + k * 32);
    }

    const float s = fminf(fmaxf(logit_scale[0], 1.0f), 100.0f);

    for (int n0 = 0; n0 < CC; n0 += 64) {
        __syncthreads();                        // previous chunk's B reads done
        {   // stage 64 prototype rows
            const int br = t >> 2, bq = t & 3;
            const unsigned short* src = Pbf + (n0 + br) * DD + bq * 64;
            unsigned short* dst = &Blds[br * LDP + bq * 64];
            #pragma unroll
            for (int i = 0; i < 8; ++i)
                *(short8*)(dst + i * 8) = *(const short8*)(src + i * 8);
        }
        __syncthreads();

        #pragma unroll
        for (int nf = 0; nf < 4; ++nf) {
            f32x4 acc = {0.f, 0.f, 0.f, 0.f};
            const unsigned short* bbase = &Blds[(nf * 16 + lrow) * LDP + lk * 8];
            #pragma unroll
            for (int k = 0; k < 8; ++k) {
                short8 b = *(const short8*)(bbase + k * 32);
                acc = __builtin_amdgcn_mfma_f32_16x16x32_bf16(a[k], b, acc, 0, 0, 0);
            }
            const int col = n0 + nf * 16 + lrow;            // C/D: col = lane&15
            const int rowbase = m0 + 16 * w + lk * 4;       //      row = (lane>>4)*4 + reg
            #pragma unroll
            for (int r = 0; r < 4; ++r)
                out[(rowbase + r) * CC + col] = acc[r] * s;
        }
    }
}

extern "C" void kernel_launch(void* const* d_in, const int* in_sizes, int n_in,
                              void* d_out, int out_size, void* d_ws, size_t ws_size,
                              hipStream_t stream) {
    const float*  S      = (const float*)d_in[0];
    const int*    labels = (const int*)d_in[1];
    const float*  Qf     = (const float*)d_in[2];
    const float*  lscale = (const float*)d_in[3];
    const float*  pshr   = (const float*)d_in[4];

    const int N_s = in_sizes[0] / DD;     // 65536
    const int N_q = in_sizes[2] / DD;     // 131072

    // workspace layout (bytes)
    float* sums          = (float*)d_ws;                                  // 512*256*4 = 524288
    float* counts        = (float*)((char*)d_ws + 524288);                // 512*4    = 2048
    float* gsum          = (float*)((char*)d_ws + 526336);                // 256*4    = 1024
    unsigned short* Pbf  = (unsigned short*)((char*)d_ws + 527360);       // 512*256*2 = 262144

    float* out   = (float*)d_out;
    float* outUC = out + (size_t)N_q * CC;

    hipMemsetAsync(d_ws, 0, 527360, stream);   // zero sums+counts+gsum each call

    class_sum_kernel<<<CC, 256, 0, stream>>>((const float4*)S, labels, sums, counts, N_s);
    centroid_kernel<<<CC / 32, 256, 0, stream>>>(sums, gsum);
    proto_kernel<<<CC, 256, 0, stream>>>(sums, counts, gsum, pshr, Pbf, outUC, N_s);
    logits_kernel<<<N_q / 64, 256, 0, stream>>>((const float4*)Qf, Pbf, lscale, out);
}

// Round 2
// 145.149 us; speedup vs baseline: 1.4317x; 1.4317x over previous
//
#include <hip/hip_runtime.h>

typedef __attribute__((ext_vector_type(4)))  float f32x4;
typedef __attribute__((ext_vector_type(16))) float f32x16;
typedef __attribute__((ext_vector_type(8)))  short short8;

#define DD 256          // feature dim
#define CC 512          // num classes
#define LDP 264         // padded LDS row stride (bf16 elems): 528B -> 4-way max conflict on b128

__device__ __forceinline__ unsigned short f2bf(float f) {
    union { float f; unsigned u; } x; x.f = f;
    unsigned r = x.u + 0x7FFFu + ((x.u >> 16) & 1u);   // RNE
    return (unsigned short)(r >> 16);
}

// ---------------- K1: per-class segment sum of normalized support rows ----------------
// grid = 1024: (class, half). 4 waves/block each scan 1/8 of labels (depth-2 prefetched),
// gather ~16 matching rows. Disjoint partial outputs -> no atomics, no zero-init needed.
__global__ __launch_bounds__(256) void class_sum_kernel(
    const float4* __restrict__ S, const int* __restrict__ labels,
    float* __restrict__ sums2, float* __restrict__ counts2, int N_s)
{
    const int c = blockIdx.x >> 1, half = blockIdx.x & 1;
    const int w = threadIdx.x >> 6, l = threadIdx.x & 63;
    const int seg  = N_s >> 3;                         // 8192 labels per wave
    const int base = half * (N_s >> 1) + w * seg;
    const int4* lab4 = (const int4*)(labels + base);
    const int iters = seg >> 8;                        // 32

    float ax = 0.f, ay = 0.f, az = 0.f, aw = 0.f;
    int cnt = 0;

    int4 p0 = lab4[l];
    int4 p1 = (iters > 1) ? lab4[64 + l] : make_int4(-1, -1, -1, -1);

    for (int it = 0; it < iters; ++it) {
        int4 lv = p0;
        p0 = p1;
        p1 = (it + 2 < iters) ? lab4[(it + 2) * 64 + l] : make_int4(-1, -1, -1, -1);
        #pragma unroll
        for (int s = 0; s < 4; ++s) {
            int lab = (s == 0) ? lv.x : (s == 1) ? lv.y : (s == 2) ? lv.z : lv.w;
            unsigned long long m = __ballot(lab == c);
            cnt += __popcll(m);
            while (m) {
                int p = __ffsll((long long)m) - 1;
                m &= m - 1;
                int row = base + (it * 64 + p) * 4 + s;
                float4 v = S[(size_t)row * 64 + l];    // lane l covers dims 4l..4l+3
                float ss = v.x*v.x + v.y*v.y + v.z*v.z + v.w*v.w;
                #pragma unroll
                for (int off = 32; off; off >>= 1) ss += __shfl_xor(ss, off);
                float inv = 1.0f / fmaxf(sqrtf(ss), 1e-8f);
                ax += v.x * inv; ay += v.y * inv; az += v.z * inv; aw += v.w * inv;
            }
        }
    }

    __shared__ float lred[4][DD];
    __shared__ float lcnt[4];
    lred[w][4*l+0] = ax; lred[w][4*l+1] = ay; lred[w][4*l+2] = az; lred[w][4*l+3] = aw;
    if (l == 0) lcnt[w] = (float)cnt;
    __syncthreads();
    int t = threadIdx.x;
    sums2[(size_t)(half * CC + c) * DD + t] = lred[0][t] + lred[1][t] + lred[2][t] + lred[3][t];
    if (t == 0) counts2[half * CC + c] = lcnt[0] + lcnt[1] + lcnt[2] + lcnt[3];
}

// ---------------- K2: centroid partials (8 blocks, no atomics) ----------------
__global__ __launch_bounds__(256) void centroid_kernel(
    const float* __restrict__ sums2, float* __restrict__ gpart)
{
    const int d = threadIdx.x, b = blockIdx.x;
    float s = 0.f;
    for (int j = 0; j < 64; ++j) {
        int c = b * 64 + j;
        s += sums2[(size_t)c * DD + d] + sums2[(size_t)(CC + c) * DD + d];
    }
    gpart[b * DD + d] = s;
}

// ---------------- K3: prototypes (shrink + renormalize) -> bf16 P, + unique_classes ----
__global__ __launch_bounds__(256) void proto_kernel(
    const float* __restrict__ sums2, const float* __restrict__ counts2,
    const float* __restrict__ gpart, const float* __restrict__ proto_shrink,
    unsigned short* __restrict__ Pbf, float* __restrict__ outUC, int N_s)
{
    const int c = blockIdx.x, d = threadIdx.x;
    float ps = proto_shrink[0];
    float ab = 1.0f / (1.0f + __expf(-ps));
    ab = fminf(fmaxf(ab, 0.0f), 0.4f);

    float sum  = sums2[(size_t)c * DD + d] + sums2[(size_t)(CC + c) * DD + d];
    float cntv = fmaxf(counts2[c] + counts2[CC + c], 1.0f);
    float g = 0.f;
    #pragma unroll
    for (int b = 0; b < 8; ++b) g += gpart[b * DD + d];
    g /= (float)N_s;

    float mean  = sum / cntv;
    float alpha = ab / sqrtf(cntv);
    float p = (1.0f - alpha) * mean + alpha * g;

    float ss = p * p;
    #pragma unroll
    for (int off = 32; off; off >>= 1) ss += __shfl_xor(ss, off);
    __shared__ float l4[4];
    if ((threadIdx.x & 63) == 0) l4[threadIdx.x >> 6] = ss;
    __syncthreads();
    ss = l4[0] + l4[1] + l4[2] + l4[3];
    float inv = 1.0f / fmaxf(sqrtf(ss), 1e-8f);
    Pbf[(size_t)c * DD + d] = f2bf(p * inv);
    if (d == 0) outUC[c] = (float)c;
}

// ---------------- K4: logits = normalize(q) @ P^T * scale ----------------
// 32x32x16 MFMA. Block = 256 thr (4 waves), M-tile 128 (wave owns 32 rows, full-K A in regs).
// Single 67.6KB LDS buffer: A staging first, then reused for reg-prefetched 64-col B chunks.
__global__ __launch_bounds__(256) void logits_kernel(
    const float4* __restrict__ Q, const unsigned short* __restrict__ Pbf,
    const float* __restrict__ logit_scale, float* __restrict__ out)
{
    __shared__ unsigned short smem[128 * LDP];   // 67584 B
    unsigned short* Alds = smem;                 // [128][LDP] during staging
    unsigned short* Blds = smem;                 // [64][LDP] during GEMM

    const int t  = threadIdx.x;
    const int m0 = blockIdx.x * 128;

    // prefetch B chunk 0 (classes 0..63) into regs
    short8 breg[8];
    {
        const int br = t >> 2, bq = t & 3;
        const unsigned short* src = Pbf + (size_t)br * DD + bq * 64;
        #pragma unroll
        for (int i = 0; i < 8; ++i) breg[i] = *(const short8*)(src + i * 8);
    }

    // stage A: 128 q rows, normalized bf16 (2 passes of 64 rows; 4 threads/row)
    #pragma unroll
    for (int pass = 0; pass < 2; ++pass) {
        const int r = pass * 64 + (t >> 2), q4 = t & 3;
        const float4* qrow = Q + (size_t)(m0 + r) * 64;
        float4 v[16];
        #pragma unroll
        for (int i = 0; i < 16; ++i) v[i] = qrow[q4 * 16 + i];
        float ss = 0.f;
        #pragma unroll
        for (int i = 0; i < 16; ++i) ss += v[i].x*v[i].x + v[i].y*v[i].y + v[i].z*v[i].z + v[i].w*v[i].w;
        ss += __shfl_xor(ss, 1); ss += __shfl_xor(ss, 2);
        float inv = 1.0f / fmaxf(sqrtf(ss), 1e-8f);
        unsigned short* dst = &Alds[r * LDP + q4 * 64];
        #pragma unroll
        for (int i = 0; i < 8; ++i) {
            short8 pk;
            float4 a = v[2*i], b = v[2*i+1];
            pk[0] = (short)f2bf(a.x*inv); pk[1] = (short)f2bf(a.y*inv);
            pk[2] = (short)f2bf(a.z*inv); pk[3] = (short)f2bf(a.w*inv);
            pk[4] = (short)f2bf(b.x*inv); pk[5] = (short)f2bf(b.y*inv);
            pk[6] = (short)f2bf(b.z*inv); pk[7] = (short)f2bf(b.w*inv);
            *(short8*)(dst + i * 8) = pk;
        }
    }
    __syncthreads();

    // load A fragments: wave w owns rows 32w..32w+31; lane l: row=32w+(l&31), k=(l>>5)*8+..
    const int w = t >> 6, l = t & 63;
    const int arow = 32 * w + (l & 31);
    const int kgrp = (l >> 5) * 8;
    short8 a[16];                                // K=256 -> 16 k-steps, 64 VGPR
    #pragma unroll
    for (int k = 0; k < 16; ++k)
        a[k] = *(const short8*)(&Alds[arow * LDP + k * 16 + kgrp]);
    __syncthreads();                             // all waves done reading A

    // write B0 to LDS, prefetch B1
    {
        const int br = t >> 2, bq = t & 3;
        unsigned short* dst = &Blds[br * LDP + bq * 64];
        #pragma unroll
        for (int i = 0; i < 8; ++i) *(short8*)(dst + i * 8) = breg[i];
        const unsigned short* src = Pbf + (size_t)(64 + br) * DD + bq * 64;
        #pragma unroll
        for (int i = 0; i < 8; ++i) breg[i] = *(const short8*)(src + i * 8);
    }
    __syncthreads();

    const float s = fminf(fmaxf(logit_scale[0], 1.0f), 100.0f);

    for (int c0 = 0; c0 < 8; ++c0) {             // 8 chunks of 64 classes
        const int n0 = c0 * 64;
        #pragma unroll
        for (int nf = 0; nf < 2; ++nf) {
            f32x16 acc;
            #pragma unroll
            for (int r = 0; r < 16; ++r) acc[r] = 0.f;
            const unsigned short* bbase = &Blds[(nf * 32 + (l & 31)) * LDP + kgrp];
            #pragma unroll
            for (int k = 0; k < 16; ++k) {
                short8 b = *(const short8*)(bbase + k * 16);
                acc = __builtin_amdgcn_mfma_f32_32x32x16_bf16(a[k], b, acc, 0, 0, 0);
            }
            // C/D 32x32: col = lane&31, row = (reg&3) + 8*(reg>>2) + 4*(lane>>5)
            const int col   = n0 + nf * 32 + (l & 31);
            const int rbase = m0 + 32 * w + 4 * (l >> 5);
            #pragma unroll
            for (int r = 0; r < 16; ++r) {
                int row = rbase + (r & 3) + 8 * (r >> 2);
                out[(size_t)row * CC + col] = acc[r] * s;
            }
        }
        if (c0 < 7) {
            __syncthreads();                     // all reads of this chunk done
            const int br = t >> 2, bq = t & 3;
            unsigned short* dst = &Blds[br * LDP + bq * 64];
            #pragma unroll
            for (int i = 0; i < 8; ++i) *(short8*)(dst + i * 8) = breg[i];
            if (c0 < 6) {
                const unsigned short* src = Pbf + (size_t)((c0 + 2) * 64 + br) * DD + bq * 64;
                #pragma unroll
                for (int i = 0; i < 8; ++i) breg[i] = *(const short8*)(src + i * 8);
            }
            __syncthreads();                     // next chunk visible
        }
    }
}

extern "C" void kernel_launch(void* const* d_in, const int* in_sizes, int n_in,
                              void* d_out, int out_size, void* d_ws, size_t ws_size,
                              hipStream_t stream) {
    const float* S      = (const float*)d_in[0];
    const int*   labels = (const int*)d_in[1];
    const float* Qf     = (const float*)d_in[2];
    const float* lscale = (const float*)d_in[3];
    const float* pshr   = (const float*)d_in[4];

    const int N_s = in_sizes[0] / DD;     // 65536
    const int N_q = in_sizes[2] / DD;     // 131072

    // workspace layout (bytes) — every slot fully written each call, no memset needed
    float* sums2         = (float*)d_ws;                                   // 2*512*256*4 = 1048576
    float* counts2       = (float*)((char*)d_ws + 1048576);                // 2*512*4    = 4096
    float* gpart         = (float*)((char*)d_ws + 1052672);                // 8*256*4    = 8192
    unsigned short* Pbf  = (unsigned short*)((char*)d_ws + 1060864);       // 512*256*2  = 262144

    float* out   = (float*)d_out;
    float* outUC = out + (size_t)N_q * CC;

    class_sum_kernel<<<2 * CC, 256, 0, stream>>>((const float4*)S, labels, sums2, counts2, N_s);
    centroid_kernel<<<8, 256, 0, stream>>>(sums2, gpart);
    proto_kernel<<<CC, 256, 0, stream>>>(sums2, counts2, gpart, pshr, Pbf, outUC, N_s);
    logits_kernel<<<N_q / 128, 256, 0, stream>>>((const float4*)Qf, Pbf, lscale, out);
}

// Round 3
// 120.708 us; speedup vs baseline: 1.7216x; 1.2025x over previous
//
#include <hip/hip_runtime.h>

typedef __attribute__((ext_vector_type(4)))  float f32x4;
typedef __attribute__((ext_vector_type(16))) float f32x16;
typedef __attribute__((ext_vector_type(8)))  short short8;

#define DD 256          // feature dim
#define CC 512          // num classes
#define LDP 264         // padded LDS row stride (bf16 elems): 528B, 16B-aligned rows, <=4-way conflict

__device__ __forceinline__ unsigned short f2bf(float f) {
    union { float f; unsigned u; } x; x.f = f;
    unsigned r = x.u + 0x7FFFu + ((x.u >> 16) & 1u);   // RNE
    return (unsigned short)(r >> 16);
}

__device__ __forceinline__ f32x4 ntload4(const f32x4* p) {
    return __builtin_nontemporal_load(p);
}

// ---------------- K1: per-class segment sum of normalized support rows ----------------
// grid = 1024: (class, half). Depth-2 pipelined gather: two matched-row loads in flight,
// reduces interleaved -> halves the serial latency chain. S loads nontemporal (read-once).
__global__ __launch_bounds__(256) void class_sum_kernel(
    const f32x4* __restrict__ S, const int* __restrict__ labels,
    float* __restrict__ sums2, float* __restrict__ counts2, int N_s)
{
    const int c = blockIdx.x >> 1, half = blockIdx.x & 1;
    const int w = threadIdx.x >> 6, l = threadIdx.x & 63;
    const int seg  = N_s >> 3;
    const int base = half * (N_s >> 1) + w * seg;
    const int4* lab4 = (const int4*)(labels + base);
    const int iters = seg >> 8;

    float ax = 0.f, ay = 0.f, az = 0.f, aw = 0.f;
    int cnt = 0;

    int4 p0v = lab4[l];
    int4 p1v = (iters > 1) ? lab4[64 + l] : make_int4(-1, -1, -1, -1);

    for (int it = 0; it < iters; ++it) {
        int4 lv = p0v;
        p0v = p1v;
        p1v = (it + 2 < iters) ? lab4[(it + 2) * 64 + l] : make_int4(-1, -1, -1, -1);
        #pragma unroll
        for (int s = 0; s < 4; ++s) {
            int lab = (s == 0) ? lv.x : (s == 1) ? lv.y : (s == 2) ? lv.z : lv.w;
            unsigned long long m = __ballot(lab == c);
            cnt += __popcll(m);
            while (m) {
                int p0 = __ffsll((long long)m) - 1; m &= m - 1;
                int p1 = -1;
                if (m) { p1 = __ffsll((long long)m) - 1; m &= m - 1; }
                int row0 = base + (it * 64 + p0) * 4 + s;
                f32x4 v0 = ntload4(&S[(size_t)row0 * 64 + l]);
                f32x4 v1 = {0.f, 0.f, 0.f, 0.f};
                if (p1 >= 0) {
                    int row1 = base + (it * 64 + p1) * 4 + s;
                    v1 = ntload4(&S[(size_t)row1 * 64 + l]);
                }
                float ss0 = v0[0]*v0[0] + v0[1]*v0[1] + v0[2]*v0[2] + v0[3]*v0[3];
                float ss1 = v1[0]*v1[0] + v1[1]*v1[1] + v1[2]*v1[2] + v1[3]*v1[3];
                #pragma unroll
                for (int off = 32; off; off >>= 1) {
                    ss0 += __shfl_xor(ss0, off);
                    ss1 += __shfl_xor(ss1, off);
                }
                float inv0 = 1.0f / fmaxf(sqrtf(ss0), 1e-8f);
                ax += v0[0]*inv0; ay += v0[1]*inv0; az += v0[2]*inv0; aw += v0[3]*inv0;
                if (p1 >= 0) {
                    float inv1 = 1.0f / fmaxf(sqrtf(ss1), 1e-8f);
                    ax += v1[0]*inv1; ay += v1[1]*inv1; az += v1[2]*inv1; aw += v1[3]*inv1;
                }
            }
        }
    }

    __shared__ float lred[4][DD];
    __shared__ float lcnt[4];
    lred[w][4*l+0] = ax; lred[w][4*l+1] = ay; lred[w][4*l+2] = az; lred[w][4*l+3] = aw;
    if (l == 0) lcnt[w] = (float)cnt;
    __syncthreads();
    int t = threadIdx.x;
    sums2[(size_t)(half * CC + c) * DD + t] = lred[0][t] + lred[1][t] + lred[2][t] + lred[3][t];
    if (t == 0) counts2[half * CC + c] = lcnt[0] + lcnt[1] + lcnt[2] + lcnt[3];
}

// ---------------- K2: centroid partials (8 blocks, no atomics) ----------------
__global__ __launch_bounds__(256) void centroid_kernel(
    const float* __restrict__ sums2, float* __restrict__ gpart)
{
    const int d = threadIdx.x, b = blockIdx.x;
    float s = 0.f;
    for (int j = 0; j < 64; ++j) {
        int c = b * 64 + j;
        s += sums2[(size_t)c * DD + d] + sums2[(size_t)(CC + c) * DD + d];
    }
    gpart[b * DD + d] = s;
}

// ---------------- K3: prototypes (shrink + renormalize) -> bf16 P, + unique_classes ----
__global__ __launch_bounds__(256) void proto_kernel(
    const float* __restrict__ sums2, const float* __restrict__ counts2,
    const float* __restrict__ gpart, const float* __restrict__ proto_shrink,
    unsigned short* __restrict__ Pbf, float* __restrict__ outUC, int N_s)
{
    const int c = blockIdx.x, d = threadIdx.x;
    float ps = proto_shrink[0];
    float ab = 1.0f / (1.0f + __expf(-ps));
    ab = fminf(fmaxf(ab, 0.0f), 0.4f);

    float sum  = sums2[(size_t)c * DD + d] + sums2[(size_t)(CC + c) * DD + d];
    float cntv = fmaxf(counts2[c] + counts2[CC + c], 1.0f);
    float g = 0.f;
    #pragma unroll
    for (int b = 0; b < 8; ++b) g += gpart[b * DD + d];
    g /= (float)N_s;

    float mean  = sum / cntv;
    float alpha = ab / sqrtf(cntv);
    float p = (1.0f - alpha) * mean + alpha * g;

    float ss = p * p;
    #pragma unroll
    for (int off = 32; off; off >>= 1) ss += __shfl_xor(ss, off);
    __shared__ float l4[4];
    if ((threadIdx.x & 63) == 0) l4[threadIdx.x >> 6] = ss;
    __syncthreads();
    ss = l4[0] + l4[1] + l4[2] + l4[3];
    float inv = 1.0f / fmaxf(sqrtf(ss), 1e-8f);
    Pbf[(size_t)c * DD + d] = f2bf(p * inv);
    if (d == 0) outUC[c] = (float)c;
}

// ---------------- K4: logits = normalize(q) @ P^T * scale ----------------
// 32x32x16 MFMA, M-tile 128, 4 waves. A staged once in LDS -> regs; B double-buffered
// in the (dead) A space. Raw s_barrier + lgkmcnt(0) ONLY -- output stores are never
// drained at barriers (counted vmcnt handled by the compiler for B prefetch regs).
__global__ __launch_bounds__(256) void logits_kernel(
    const float4* __restrict__ Q, const unsigned short* __restrict__ Pbf,
    const float* __restrict__ logit_scale, float* __restrict__ out)
{
    __shared__ unsigned short smem[128 * LDP];   // 67584 B -> 2 blocks/CU
    unsigned short* bufA = smem;                 // [128][LDP] A staging
    unsigned short* buf0 = smem;                 // B buffer 0 (reuses A rows 0..63)
    unsigned short* buf1 = smem + 64 * LDP;      // B buffer 1 (reuses A rows 64..127)

    const int t  = threadIdx.x;
    const int m0 = blockIdx.x * 128;
    const int br = t >> 2, bq = t & 3;
    const unsigned short* Pb = Pbf + (size_t)br * DD + bq * 64;

    // prefetch B chunk 0 into regs (overlaps A staging)
    short8 breg[8];
    #pragma unroll
    for (int i = 0; i < 8; ++i) breg[i] = *(const short8*)(Pb + i * 8);

    // ---- A stage: 128 q rows, normalized bf16 -> LDS (2 passes, 4 threads/row) ----
    #pragma unroll
    for (int pass = 0; pass < 2; ++pass) {
        const int r = pass * 64 + (t >> 2), q4 = t & 3;
        const float4* qrow = Q + (size_t)(m0 + r) * 64;
        float4 v[16];
        #pragma unroll
        for (int i = 0; i < 16; ++i) v[i] = qrow[q4 * 16 + i];
        float ss = 0.f;
        #pragma unroll
        for (int i = 0; i < 16; ++i) ss += v[i].x*v[i].x + v[i].y*v[i].y + v[i].z*v[i].z + v[i].w*v[i].w;
        ss += __shfl_xor(ss, 1); ss += __shfl_xor(ss, 2);
        float inv = 1.0f / fmaxf(sqrtf(ss), 1e-8f);
        unsigned short* dst = &bufA[r * LDP + q4 * 64];
        #pragma unroll
        for (int i = 0; i < 8; ++i) {
            short8 pk;
            float4 a0 = v[2*i], b0 = v[2*i+1];
            pk[0] = (short)f2bf(a0.x*inv); pk[1] = (short)f2bf(a0.y*inv);
            pk[2] = (short)f2bf(a0.z*inv); pk[3] = (short)f2bf(a0.w*inv);
            pk[4] = (short)f2bf(b0.x*inv); pk[5] = (short)f2bf(b0.y*inv);
            pk[6] = (short)f2bf(b0.z*inv); pk[7] = (short)f2bf(b0.w*inv);
            *(short8*)(dst + i * 8) = pk;
        }
    }
    __builtin_amdgcn_sched_barrier(0);
    asm volatile("s_waitcnt lgkmcnt(0)");
    __builtin_amdgcn_sched_barrier(0);
    __builtin_amdgcn_s_barrier();                // A visible to all
    __builtin_amdgcn_sched_barrier(0);

    // ---- A fragments -> registers (wave w owns rows 32w..32w+31) ----
    const int w = t >> 6, l = t & 63;
    const int arow = 32 * w + (l & 31);
    const int kgrp = (l >> 5) * 8;
    short8 a[16];
    #pragma unroll
    for (int k = 0; k < 16; ++k)
        a[k] = *(const short8*)(&bufA[arow * LDP + k * 16 + kgrp]);
    __builtin_amdgcn_sched_barrier(0);
    asm volatile("s_waitcnt lgkmcnt(0)");        // my frag reads retired
    __builtin_amdgcn_sched_barrier(0);
    __builtin_amdgcn_s_barrier();                // all waves done reading A
    __builtin_amdgcn_sched_barrier(0);

    // ---- write B0, prefetch B1 ----
    {
        unsigned short* dst = &buf0[br * LDP + bq * 64];
        #pragma unroll
        for (int i = 0; i < 8; ++i) *(short8*)(dst + i * 8) = breg[i];
        const unsigned short* src = Pb + (size_t)64 * DD;
        #pragma unroll
        for (int i = 0; i < 8; ++i) breg[i] = *(const short8*)(src + i * 8);
    }
    __builtin_amdgcn_sched_barrier(0);
    asm volatile("s_waitcnt lgkmcnt(0)");
    __builtin_amdgcn_sched_barrier(0);
    __builtin_amdgcn_s_barrier();                // buf0 ready
    __builtin_amdgcn_sched_barrier(0);

    const float s = fminf(fmaxf(logit_scale[0], 1.0f), 100.0f);

    unsigned short* bufR = buf0;
    unsigned short* bufW = buf1;

    for (int c0 = 0; c0 < 8; ++c0) {
        // stage chunk c0+1 into bufW (compiler inserts counted vmcnt for breg)
        if (c0 < 7) {
            unsigned short* dst = &bufW[br * LDP + bq * 64];
            #pragma unroll
            for (int i = 0; i < 8; ++i) *(short8*)(dst + i * 8) = breg[i];
        }
        // prefetch chunk c0+2
        if (c0 < 6) {
            const unsigned short* src = Pb + (size_t)(c0 + 2) * 64 * DD;
            #pragma unroll
            for (int i = 0; i < 8; ++i) breg[i] = *(const short8*)(src + i * 8);
        }
        // compute from bufR
        const int n0 = c0 * 64;
        #pragma unroll
        for (int nf = 0; nf < 2; ++nf) {
            f32x16 acc;
            #pragma unroll
            for (int r = 0; r < 16; ++r) acc[r] = 0.f;
            const unsigned short* bbase = &bufR[(nf * 32 + (l & 31)) * LDP + kgrp];
            __builtin_amdgcn_s_setprio(1);
            #pragma unroll
            for (int k = 0; k < 16; ++k) {
                short8 b = *(const short8*)(bbase + k * 16);
                acc = __builtin_amdgcn_mfma_f32_32x32x16_bf16(a[k], b, acc, 0, 0, 0);
            }
            __builtin_amdgcn_s_setprio(0);
            // C/D 32x32: col = lane&31, row = (reg&3) + 8*(reg>>2) + 4*(lane>>5)
            const int col   = n0 + nf * 32 + (l & 31);
            const int rbase = m0 + 32 * w + 4 * (l >> 5);
            #pragma unroll
            for (int r = 0; r < 16; ++r) {
                int row = rbase + (r & 3) + 8 * (r >> 2);
                __builtin_nontemporal_store(acc[r] * s, &out[(size_t)row * CC + col]);
            }
        }
        if (c0 < 7) {
            __builtin_amdgcn_sched_barrier(0);
            asm volatile("s_waitcnt lgkmcnt(0)");    // my ds_write + ds_read retired
            __builtin_amdgcn_sched_barrier(0);
            __builtin_amdgcn_s_barrier();            // bufW ready / bufR free
            __builtin_amdgcn_sched_barrier(0);
            unsigned short* tmp = bufR; bufR = bufW; bufW = tmp;
        }
    }
}

extern "C" void kernel_launch(void* const* d_in, const int* in_sizes, int n_in,
                              void* d_out, int out_size, void* d_ws, size_t ws_size,
                              hipStream_t stream) {
    const float* S      = (const float*)d_in[0];
    const int*   labels = (const int*)d_in[1];
    const float* Qf     = (const float*)d_in[2];
    const float* lscale = (const float*)d_in[3];
    const float* pshr   = (const float*)d_in[4];

    const int N_s = in_sizes[0] / DD;     // 65536
    const int N_q = in_sizes[2] / DD;     // 131072

    float* sums2         = (float*)d_ws;                                   // 2*512*256*4
    float* counts2       = (float*)((char*)d_ws + 1048576);                // 2*512*4
    float* gpart         = (float*)((char*)d_ws + 1052672);                // 8*256*4
    unsigned short* Pbf  = (unsigned short*)((char*)d_ws + 1060864);       // 512*256*2

    float* out   = (float*)d_out;
    float* outUC = out + (size_t)N_q * CC;

    class_sum_kernel<<<2 * CC, 256, 0, stream>>>((const f32x4*)S, labels, sums2, counts2, N_s);
    centroid_kernel<<<8, 256, 0, stream>>>(sums2, gpart);
    proto_kernel<<<CC, 256, 0, stream>>>(sums2, counts2, gpart, pshr, Pbf, outUC, N_s);
    logits_kernel<<<N_q / 128, 256, 0, stream>>>((const float4*)Qf, Pbf, lscale, out);
}